// Round 2
// baseline (153.832 us; speedup 1.0000x reference)
//
#include <hip/hip_runtime.h>
#include <hip/hip_bf16.h>

#define BB 256
#define DD 512
#define CNUM 100000
#define CPAD 100096
#define NCHUNK 782
#define NPART (NCHUNK * 2)

typedef __attribute__((ext_vector_type(8))) short bf16x8;
typedef __attribute__((ext_vector_type(4))) float f32x4;

typedef __attribute__((address_space(1))) void gvoid_t;
typedef __attribute__((address_space(3))) void lvoid_t;

__device__ __forceinline__ void gload16(const void* g, void* l) {
  __builtin_amdgcn_global_load_lds((const gvoid_t*)g, (lvoid_t*)l, 16, 0, 0);
}

__device__ __forceinline__ unsigned short f2bf(float f) {
  union { float f; unsigned int u; } v; v.f = f;
  unsigned int u = v.u;
  unsigned int r = u + 0x7FFFu + ((u >> 16) & 1u);
  return (unsigned short)(r >> 16);
}

// ---------------- Pass 0: normalize x rows -> bf16, per-sample margin trig ----
__global__ void k_prep_x(const float* __restrict__ x, const float* __restrict__ xnrm,
                         unsigned short* __restrict__ xn, float* __restrict__ cm,
                         float* __restrict__ sm) {
  int b = blockIdx.x;
  int lane = threadIdx.x;  // 64 threads
  const float4* xr = (const float4*)(x + (size_t)b * DD);
  float4 v0 = xr[lane * 2];
  float4 v1 = xr[lane * 2 + 1];
  float ss = v0.x * v0.x + v0.y * v0.y + v0.z * v0.z + v0.w * v0.w +
             v1.x * v1.x + v1.y * v1.y + v1.z * v1.z + v1.w * v1.w;
#pragma unroll
  for (int msk = 1; msk < 64; msk <<= 1) ss += __shfl_xor(ss, msk, 64);
  float inv = rsqrtf(ss);
  unsigned int p0 = (unsigned int)f2bf(v0.x * inv) | ((unsigned int)f2bf(v0.y * inv) << 16);
  unsigned int p1 = (unsigned int)f2bf(v0.z * inv) | ((unsigned int)f2bf(v0.w * inv) << 16);
  unsigned int p2 = (unsigned int)f2bf(v1.x * inv) | ((unsigned int)f2bf(v1.y * inv) << 16);
  unsigned int p3 = (unsigned int)f2bf(v1.z * inv) | ((unsigned int)f2bf(v1.w * inv) << 16);
  *(uint4*)(xn + (size_t)b * DD + lane * 8) = make_uint4(p0, p1, p2, p3);
  if (lane == 0) {
    float a = xnrm[b];
    float marg = 0.0035f * (a - 10.0f) + 0.45f;  // (U_M-L_M)/(U_A-L_A)=0.0035
    cm[b] = cosf(marg);
    sm[b] = sinf(marg);
  }
}

// ---------------- Pass 1: normalize weight rows -> bf16 (padded rows zeroed) ---
__global__ void k_prep_w(const float* __restrict__ w, unsigned short* __restrict__ wn) {
  int row = blockIdx.x * 4 + (threadIdx.x >> 6);
  int lane = threadIdx.x & 63;
  unsigned short* out = wn + (size_t)row * DD + lane * 8;
  if (row < CNUM) {
    const float4* wr = (const float4*)(w + (size_t)row * DD);
    float4 v0 = wr[lane * 2];
    float4 v1 = wr[lane * 2 + 1];
    float ss = v0.x * v0.x + v0.y * v0.y + v0.z * v0.z + v0.w * v0.w +
               v1.x * v1.x + v1.y * v1.y + v1.z * v1.z + v1.w * v1.w;
#pragma unroll
    for (int msk = 1; msk < 64; msk <<= 1) ss += __shfl_xor(ss, msk, 64);
    float inv = rsqrtf(ss);
    unsigned int p0 = (unsigned int)f2bf(v0.x * inv) | ((unsigned int)f2bf(v0.y * inv) << 16);
    unsigned int p1 = (unsigned int)f2bf(v0.z * inv) | ((unsigned int)f2bf(v0.w * inv) << 16);
    unsigned int p2 = (unsigned int)f2bf(v1.x * inv) | ((unsigned int)f2bf(v1.y * inv) << 16);
    unsigned int p3 = (unsigned int)f2bf(v1.z * inv) | ((unsigned int)f2bf(v1.w * inv) << 16);
    *(uint4*)out = make_uint4(p0, p1, p2, p3);
  } else {
    *(uint4*)out = make_uint4(0, 0, 0, 0);
  }
}

// ---------------- Pass 2: fused cos-matrix GEMM + margin + per-tile LSE partials
__global__ __launch_bounds__(512) void k_gemm(
    const unsigned short* __restrict__ xn, const unsigned short* __restrict__ wn,
    const int* __restrict__ labels, const float* __restrict__ cmv,
    const float* __restrict__ smv, float2* __restrict__ part, float* __restrict__ tgt) {
  __shared__ short Xs[BB * 64];    // [row][k] 32KB
  __shared__ short Wcs[128 * 64];  // [col][k] 16KB
  __shared__ int sLab[BB];
  __shared__ float sCm[BB], sSm[BB];

  int tid = threadIdx.x, wave = tid >> 6, lane = tid & 63;
  int wm = wave >> 1, wq = wave & 1;  // 4x2 wave grid: wave tile 64 rows x 64 cols
  int cbase = blockIdx.x * 128;

  if (tid < BB) {
    sLab[tid] = labels[tid];
    sCm[tid] = cmv[tid];
    sSm[tid] = smv[tid];
  }

  f32x4 acc[4][4];
#pragma unroll
  for (int m = 0; m < 4; ++m)
#pragma unroll
    for (int n = 0; n < 4; ++n) acc[m][n] = (f32x4){0.f, 0.f, 0.f, 0.f};

  int lr = lane >> 3, lk = lane & 7;

  for (int kc = 0; kc < 8; ++kc) {
    int k0 = kc * 64;
    __syncthreads();
#pragma unroll
    for (int i = 0; i < 4; ++i) {
      int rbase = i * 64 + wave * 8;
      gload16(xn + (size_t)(rbase + lr) * DD + k0 + lk * 8, &Xs[rbase * 64]);
    }
#pragma unroll
    for (int i = 0; i < 2; ++i) {
      int rbase = i * 64 + wave * 8;
      gload16(wn + (size_t)(cbase + rbase + lr) * DD + k0 + lk * 8, &Wcs[rbase * 64]);
    }
    __syncthreads();
#pragma unroll
    for (int ks = 0; ks < 2; ++ks) {
      int krd = ks * 32 + (lane >> 4) * 8;
      bf16x8 af[4], bfr[4];
#pragma unroll
      for (int m = 0; m < 4; ++m)
        af[m] = *(const bf16x8*)&Xs[(wm * 64 + m * 16 + (lane & 15)) * 64 + krd];
#pragma unroll
      for (int n = 0; n < 4; ++n)
        bfr[n] = *(const bf16x8*)&Wcs[(wq * 64 + n * 16 + (lane & 15)) * 64 + krd];
#pragma unroll
      for (int m = 0; m < 4; ++m)
#pragma unroll
        for (int n = 0; n < 4; ++n)
          acc[m][n] = __builtin_amdgcn_mfma_f32_16x16x32_bf16(af[m], bfr[n], acc[m][n], 0, 0, 0);
    }
  }

  // Epilogue: logits + margin at label col + per-row (max, sumexp) over this
  // wave's 64 cols.  C/D layout: col = lane&15, row = (lane>>4)*4 + reg.
  int g = lane >> 4, cb = lane & 15;
#pragma unroll
  for (int m = 0; m < 4; ++m) {
#pragma unroll
    for (int r = 0; r < 4; ++r) {
      int row = wm * 64 + m * 16 + g * 4 + r;
      int lab = sLab[row];
      float cmr = sCm[row], smr = sSm[row];
      float lg[4];
      float vmax = -1e30f;
#pragma unroll
      for (int n = 0; n < 4; ++n) {
        int col = cbase + wq * 64 + n * 16 + cb;
        float cv = acc[m][n][r];
        cv = fminf(1.0f, fmaxf(-1.0f, cv));
        float logit;
        if (col == lab) {
          float st = sqrtf(fmaxf(0.0f, 1.0f - cv * cv));
          float cm2 = cv * cmr - st * smr;
          logit = 64.0f * (cv > 0.0f ? cm2 : cv);
          tgt[row] = logit;  // exactly one (row,col==label) in the whole grid
        } else {
          logit = 64.0f * cv;
        }
        if (col >= CNUM) logit = -1e30f;
        lg[n] = logit;
        vmax = fmaxf(vmax, logit);
      }
#pragma unroll
      for (int msk = 1; msk < 16; msk <<= 1) vmax = fmaxf(vmax, __shfl_xor(vmax, msk, 64));
      float s = 0.0f;
#pragma unroll
      for (int n = 0; n < 4; ++n) s += __expf(lg[n] - vmax);
#pragma unroll
      for (int msk = 1; msk < 16; msk <<= 1) s += __shfl_xor(s, msk, 64);
      if (cb == 0) part[(size_t)row * NPART + blockIdx.x * 2 + wq] = make_float2(vmax, s);
    }
  }
}

// ---------------- Pass 3: per-row LSE merge over 1564 partials -> ce[b] -------
__global__ void k_merge(const float2* __restrict__ part, const float* __restrict__ tgt,
                        float* __restrict__ ce) {
  int b = blockIdx.x, t = threadIdx.x;
  float m = -1e30f, s = 0.0f;
  for (int i = t; i < NPART; i += 256) {
    float2 p = part[(size_t)b * NPART + i];
    float nm = fmaxf(m, p.x);
    s = s * __expf(m - nm) + p.y * __expf(p.x - nm);
    m = nm;
  }
  __shared__ float smx[256], ssm[256];
  smx[t] = m;
  ssm[t] = s;
  __syncthreads();
  for (int off = 128; off > 0; off >>= 1) {
    if (t < off) {
      float m2 = smx[t + off], s2 = ssm[t + off];
      float nm = fmaxf(smx[t], m2);
      ssm[t] = ssm[t] * __expf(smx[t] - nm) + s2 * __expf(m2 - nm);
      smx[t] = nm;
    }
    __syncthreads();
  }
  if (t == 0) ce[b] = smx[0] + logf(ssm[0]) - tgt[b];
}

// ---------------- Pass 4: final scalar ---------------------------------------
__global__ void k_final(const float* __restrict__ ce, const float* __restrict__ xnrm,
                        float* __restrict__ out) {
  int t = threadIdx.x;
  float cv = ce[t];
  float a = xnrm[t];
  float gv = a * (1.0f / (110.0f * 110.0f)) + 1.0f / a;
  __shared__ float s1[256], s2[256];
  s1[t] = cv;
  s2[t] = gv;
  __syncthreads();
  for (int off = 128; off > 0; off >>= 1) {
    if (t < off) {
      s1[t] += s1[t + off];
      s2[t] += s2[t + off];
    }
    __syncthreads();
  }
  if (t == 0) out[0] = s1[0] * (1.0f / 256.0f) + 35.0f * s2[0] * (1.0f / 256.0f);
}

extern "C" void kernel_launch(void* const* d_in, const int* in_sizes, int n_in,
                              void* d_out, int out_size, void* d_ws, size_t ws_size,
                              hipStream_t stream) {
  const float* x = (const float*)d_in[0];
  const float* xnrm = (const float*)d_in[1];
  const int* labels = (const int*)d_in[2];
  const float* w = (const float*)d_in[3];

  char* ws = (char*)d_ws;
  unsigned short* WN = (unsigned short*)ws;  // CPAD*DD bf16 = 102.5 MB
  size_t off = (size_t)CPAD * DD * 2;
  unsigned short* XN = (unsigned short*)(ws + off);
  off += (size_t)BB * DD * 2;
  float* CM = (float*)(ws + off);  off += 1024;
  float* SM = (float*)(ws + off);  off += 1024;
  float* TGT = (float*)(ws + off); off += 1024;
  float* CE = (float*)(ws + off);  off += 1024;
  float2* PART = (float2*)(ws + off);  // 256 * 1564 * 8B = 3.2 MB

  k_prep_x<<<BB, 64, 0, stream>>>(x, xnrm, XN, CM, SM);
  k_prep_w<<<CPAD / 4, 256, 0, stream>>>(w, WN);
  k_gemm<<<NCHUNK, 512, 0, stream>>>(XN, WN, labels, CM, SM, PART, TGT);
  k_merge<<<BB, 256, 0, stream>>>(PART, TGT, CE);
  k_final<<<1, 256, 0, stream>>>(CE, xnrm, (float*)d_out);
}

// Round 3
// 83.213 us; speedup vs baseline: 1.8486x; 1.8486x over previous
//
#include <hip/hip_runtime.h>
#include <hip/hip_bf16.h>

#define BB 256
#define DD 512
#define CNUM 100000
#define CPAD 100096
#define NCHUNK 782          // CPAD / 128
#define NPART (NCHUNK * 2)

typedef __attribute__((ext_vector_type(8))) short bf16x8;
typedef __attribute__((ext_vector_type(4))) float f32x4;

typedef __attribute__((address_space(1))) void gvoid_t;
typedef __attribute__((address_space(3))) void lvoid_t;

__device__ __forceinline__ void gload16(const void* g, void* l) {
  __builtin_amdgcn_global_load_lds((const gvoid_t*)g, (lvoid_t*)l, 16, 0, 0);
}

__device__ __forceinline__ unsigned short f2bf(float f) {
  union { float f; unsigned int u; } v; v.f = f;
  unsigned int u = v.u;
  unsigned int r = u + 0x7FFFu + ((u >> 16) & 1u);
  return (unsigned short)(r >> 16);
}

// ---------------- Pass 0: normalize x rows -> bf16, per-sample margin trig ----
__global__ void k_prep_x(const float* __restrict__ x, const float* __restrict__ xnrm,
                         unsigned short* __restrict__ xn, float* __restrict__ cm,
                         float* __restrict__ sm) {
  int b = blockIdx.x;
  int lane = threadIdx.x;  // 64 threads
  const float4* xr = (const float4*)(x + (size_t)b * DD);
  float4 v0 = xr[lane * 2];
  float4 v1 = xr[lane * 2 + 1];
  float ss = v0.x * v0.x + v0.y * v0.y + v0.z * v0.z + v0.w * v0.w +
             v1.x * v1.x + v1.y * v1.y + v1.z * v1.z + v1.w * v1.w;
#pragma unroll
  for (int msk = 1; msk < 64; msk <<= 1) ss += __shfl_xor(ss, msk, 64);
  float inv = rsqrtf(ss);
  unsigned int p0 = (unsigned int)f2bf(v0.x * inv) | ((unsigned int)f2bf(v0.y * inv) << 16);
  unsigned int p1 = (unsigned int)f2bf(v0.z * inv) | ((unsigned int)f2bf(v0.w * inv) << 16);
  unsigned int p2 = (unsigned int)f2bf(v1.x * inv) | ((unsigned int)f2bf(v1.y * inv) << 16);
  unsigned int p3 = (unsigned int)f2bf(v1.z * inv) | ((unsigned int)f2bf(v1.w * inv) << 16);
  *(uint4*)(xn + (size_t)b * DD + lane * 8) = make_uint4(p0, p1, p2, p3);
  if (lane == 0) {
    float a = xnrm[b];
    float marg = 0.0035f * (a - 10.0f) + 0.45f;  // (U_M-L_M)/(U_A-L_A)=0.0035
    cm[b] = cosf(marg);
    sm[b] = sinf(marg);
  }
}

// ---------------- Pass 1: fused W-normalize + cos GEMM + margin + LSE partials -
// W is read ONCE as fp32, per-row sum-of-squares computed on the fly,
// converted to bf16 into XOR-swizzled LDS; epilogue scales by rsqrt(ss).
__global__ __launch_bounds__(512) void k_gemm(
    const unsigned short* __restrict__ xn, const float* __restrict__ w,
    const int* __restrict__ labels, const float* __restrict__ cmv,
    const float* __restrict__ smv, float2* __restrict__ part, float* __restrict__ tgt) {
  __shared__ short Xs[BB * 64];    // [row][k] bf16, XOR-swizzled, 32 KB
  __shared__ short Ws[128 * 64];   // [col][k] bf16, XOR-swizzled, 16 KB
  __shared__ float sInvW[128];
  __shared__ int sLab[BB];
  __shared__ float sCm[BB], sSm[BB];

  int tid = threadIdx.x, wave = tid >> 6, lane = tid & 63;
  int wm = wave >> 1, wq = wave & 1;  // 4x2 wave grid: 64 rows x 64 cols per wave
  int cbase = blockIdx.x * 128;

  if (tid < BB) {
    sLab[tid] = labels[tid];
    sCm[tid] = cmv[tid];
    sSm[tid] = smv[tid];
  }

  f32x4 acc[4][4];
#pragma unroll
  for (int m = 0; m < 4; ++m)
#pragma unroll
    for (int n = 0; n < 4; ++n) acc[m][n] = (f32x4){0.f, 0.f, 0.f, 0.f};

  // X staging (global_load_lds, linear dest): pre-swizzle the global k-offset
  // so that LDS layout matches elem ^= (row&7)<<3.  row&7 == lane>>3 here.
  int lr = lane >> 3;
  int lk = (lane & 7) ^ lr;

  // W reg-staging: 4 threads per class row, 16 floats (4x float4) each.
  int wrow = tid >> 2, wseg = tid & 3;
  bool wvalid = (cbase + wrow) < CNUM;
  const float* wptr = w + (size_t)(cbase + wrow) * DD + wseg * 16;
  float ssacc = 0.0f;
  int wsw0 = wrow * 64 + ((wseg * 16) ^ ((wrow & 7) << 3));
  int wsw1 = wrow * 64 + ((wseg * 16 + 8) ^ ((wrow & 7) << 3));

  for (int kc = 0; kc < 8; ++kc) {
    int k0 = kc * 64;
    // Issue W global loads early (overlaps previous MFMA phase).
    float4 a0, a1, a2, a3;
    if (wvalid) {
      const float4* wp = (const float4*)(wptr + k0);
      a0 = wp[0]; a1 = wp[1]; a2 = wp[2]; a3 = wp[3];
    } else {
      a0 = a1 = a2 = a3 = make_float4(0.f, 0.f, 0.f, 0.f);
    }
    __syncthreads();  // previous tile's MFMA reads complete
#pragma unroll
    for (int i = 0; i < 4; ++i) {
      int rbase = i * 64 + wave * 8;
      gload16(xn + (size_t)(rbase + lr) * DD + k0 + lk * 8, &Xs[rbase * 64]);
    }
    // sum-of-squares + bf16 convert + swizzled LDS write
    ssacc += a0.x * a0.x + a0.y * a0.y + a0.z * a0.z + a0.w * a0.w +
             a1.x * a1.x + a1.y * a1.y + a1.z * a1.z + a1.w * a1.w +
             a2.x * a2.x + a2.y * a2.y + a2.z * a2.z + a2.w * a2.w +
             a3.x * a3.x + a3.y * a3.y + a3.z * a3.z + a3.w * a3.w;
    unsigned int q0 = (unsigned int)f2bf(a0.x) | ((unsigned int)f2bf(a0.y) << 16);
    unsigned int q1 = (unsigned int)f2bf(a0.z) | ((unsigned int)f2bf(a0.w) << 16);
    unsigned int q2 = (unsigned int)f2bf(a1.x) | ((unsigned int)f2bf(a1.y) << 16);
    unsigned int q3 = (unsigned int)f2bf(a1.z) | ((unsigned int)f2bf(a1.w) << 16);
    unsigned int q4 = (unsigned int)f2bf(a2.x) | ((unsigned int)f2bf(a2.y) << 16);
    unsigned int q5 = (unsigned int)f2bf(a2.z) | ((unsigned int)f2bf(a2.w) << 16);
    unsigned int q6 = (unsigned int)f2bf(a3.x) | ((unsigned int)f2bf(a3.y) << 16);
    unsigned int q7 = (unsigned int)f2bf(a3.z) | ((unsigned int)f2bf(a3.w) << 16);
    *(uint4*)&Ws[wsw0] = make_uint4(q0, q1, q2, q3);
    *(uint4*)&Ws[wsw1] = make_uint4(q4, q5, q6, q7);
    __syncthreads();  // drains gload_lds (vmcnt) + ds_writes (lgkmcnt)
#pragma unroll
    for (int ks = 0; ks < 2; ++ks) {
      int krd = ks * 32 + (lane >> 4) * 8;
      int swz = (lane & 7) << 3;  // row&7 == lane&7 for both A and B fragment rows
      bf16x8 af[4], bfr[4];
#pragma unroll
      for (int m = 0; m < 4; ++m) {
        int ra = wm * 64 + m * 16 + (lane & 15);
        af[m] = *(const bf16x8*)&Xs[ra * 64 + (krd ^ swz)];
      }
#pragma unroll
      for (int n = 0; n < 4; ++n) {
        int rb = wq * 64 + n * 16 + (lane & 15);
        bfr[n] = *(const bf16x8*)&Ws[rb * 64 + (krd ^ swz)];
      }
#pragma unroll
      for (int m = 0; m < 4; ++m)
#pragma unroll
        for (int n = 0; n < 4; ++n)
          acc[m][n] = __builtin_amdgcn_mfma_f32_16x16x32_bf16(af[m], bfr[n], acc[m][n], 0, 0, 0);
    }
  }

  // Per-row inverse norm: reduce ss over the 4 threads sharing a class row
  // (consecutive lanes), then publish.
  ssacc += __shfl_xor(ssacc, 1, 64);
  ssacc += __shfl_xor(ssacc, 2, 64);
  if (wseg == 0) sInvW[wrow] = wvalid ? rsqrtf(ssacc) : 0.0f;
  __syncthreads();

  // Epilogue: cos = acc * invW, clamp, margin at label col, per-row (max, sumexp)
  // over this wave's 64 cols.  C/D layout: col = lane&15, row = (lane>>4)*4 + reg.
  int g = lane >> 4, cb = lane & 15;
  float invc[4];
#pragma unroll
  for (int n = 0; n < 4; ++n) invc[n] = sInvW[wq * 64 + n * 16 + cb];
#pragma unroll
  for (int m = 0; m < 4; ++m) {
#pragma unroll
    for (int r = 0; r < 4; ++r) {
      int row = wm * 64 + m * 16 + g * 4 + r;
      int lab = sLab[row];
      float cmr = sCm[row], smr = sSm[row];
      float lg[4];
      float vmax = -1e30f;
#pragma unroll
      for (int n = 0; n < 4; ++n) {
        int col = cbase + wq * 64 + n * 16 + cb;
        float cv = acc[m][n][r] * invc[n];
        cv = fminf(1.0f, fmaxf(-1.0f, cv));
        float logit;
        if (col == lab) {
          float st = sqrtf(fmaxf(0.0f, 1.0f - cv * cv));
          float cm2 = cv * cmr - st * smr;
          logit = 64.0f * (cv > 0.0f ? cm2 : cv);
          tgt[row] = logit;  // exactly one (row, col==label) in the whole grid
        } else {
          logit = 64.0f * cv;
        }
        if (col >= CNUM) logit = -1e30f;
        lg[n] = logit;
        vmax = fmaxf(vmax, logit);
      }
#pragma unroll
      for (int msk = 1; msk < 16; msk <<= 1) vmax = fmaxf(vmax, __shfl_xor(vmax, msk, 64));
      float s = 0.0f;
#pragma unroll
      for (int n = 0; n < 4; ++n) s += __expf(lg[n] - vmax);
#pragma unroll
      for (int msk = 1; msk < 16; msk <<= 1) s += __shfl_xor(s, msk, 64);
      if (cb == 0) part[(size_t)row * NPART + blockIdx.x * 2 + wq] = make_float2(vmax, s);
    }
  }
}

// ---------------- Pass 2: per-row LSE merge over 1564 partials -> ce[b] -------
__global__ void k_merge(const float2* __restrict__ part, const float* __restrict__ tgt,
                        float* __restrict__ ce) {
  int b = blockIdx.x, t = threadIdx.x;
  float m = -1e30f, s = 0.0f;
  for (int i = t; i < NPART; i += 256) {
    float2 p = part[(size_t)b * NPART + i];
    float nm = fmaxf(m, p.x);
    s = s * __expf(m - nm) + p.y * __expf(p.x - nm);
    m = nm;
  }
  __shared__ float smx[256], ssm[256];
  smx[t] = m;
  ssm[t] = s;
  __syncthreads();
  for (int off = 128; off > 0; off >>= 1) {
    if (t < off) {
      float m2 = smx[t + off], s2 = ssm[t + off];
      float nm = fmaxf(smx[t], m2);
      ssm[t] = ssm[t] * __expf(smx[t] - nm) + s2 * __expf(m2 - nm);
      smx[t] = nm;
    }
    __syncthreads();
  }
  if (t == 0) ce[b] = smx[0] + logf(ssm[0]) - tgt[b];
}

// ---------------- Pass 3: final scalar ---------------------------------------
__global__ void k_final(const float* __restrict__ ce, const float* __restrict__ xnrm,
                        float* __restrict__ out) {
  int t = threadIdx.x;
  float cv = ce[t];
  float a = xnrm[t];
  float gv = a * (1.0f / (110.0f * 110.0f)) + 1.0f / a;
  __shared__ float s1[256], s2[256];
  s1[t] = cv;
  s2[t] = gv;
  __syncthreads();
  for (int off = 128; off > 0; off >>= 1) {
    if (t < off) {
      s1[t] += s1[t + off];
      s2[t] += s2[t + off];
    }
    __syncthreads();
  }
  if (t == 0) out[0] = s1[0] * (1.0f / 256.0f) + 35.0f * s2[0] * (1.0f / 256.0f);
}

extern "C" void kernel_launch(void* const* d_in, const int* in_sizes, int n_in,
                              void* d_out, int out_size, void* d_ws, size_t ws_size,
                              hipStream_t stream) {
  const float* x = (const float*)d_in[0];
  const float* xnrm = (const float*)d_in[1];
  const int* labels = (const int*)d_in[2];
  const float* w = (const float*)d_in[3];

  char* ws = (char*)d_ws;
  unsigned short* XN = (unsigned short*)ws;           // 256*512 bf16 = 256 KB
  size_t off = (size_t)BB * DD * 2;
  float* CM = (float*)(ws + off);  off += 1024;
  float* SM = (float*)(ws + off);  off += 1024;
  float* TGT = (float*)(ws + off); off += 1024;
  float* CE = (float*)(ws + off);  off += 1024;
  float2* PART = (float2*)(ws + off);  // 256 * 1564 * 8B = 3.2 MB

  k_prep_x<<<BB, 64, 0, stream>>>(x, xnrm, XN, CM, SM);
  k_gemm<<<NCHUNK, 512, 0, stream>>>(XN, w, labels, CM, SM, PART, TGT);
  k_merge<<<BB, 256, 0, stream>>>(PART, TGT, CE);
  k_final<<<1, 256, 0, stream>>>(CE, xnrm, (float*)d_out);
}